// Round 11
// baseline (334.310 us; speedup 1.0000x reference)
//
#include <hip/hip_runtime.h>
#include <hip/hip_bf16.h>

#define NEG_ATT 0.2f
#define NEG_ACT 0.01f

typedef __attribute__((ext_vector_type(8))) short short8;
typedef __attribute__((ext_vector_type(4))) float f32x4;

__device__ __forceinline__ unsigned short f2bf(float f) {
    unsigned int u = __float_as_uint(f);
    unsigned int r = (u + 0x7fff + ((u >> 16) & 1)) >> 16;  // RNE
    return (unsigned short)r;
}
__device__ __forceinline__ float b2f(unsigned short h) {
    return __uint_as_float((unsigned int)h << 16);
}

// ---------------- CSR build ----------------

#define SCAN_CHUNK 1024
// deg holds edge-counts only (self-loop added as +1 here)
__global__ void scan1(const int* __restrict__ deg, int* __restrict__ offs,
                      int* blocksum, int Nn) {
    __shared__ int sh[256];
    int b = blockIdx.x, t = threadIdx.x;
    int base = b * SCAN_CHUNK + t * 4;
    int v[4];
    int s = 0;
    for (int j = 0; j < 4; j++) {
        int idx = base + j;
        v[j] = (idx < Nn) ? deg[idx] + 1 : 0;
        s += v[j];
    }
    sh[t] = s;
    __syncthreads();
    for (int off = 1; off < 256; off <<= 1) {
        int x = (t >= off) ? sh[t - off] : 0;
        __syncthreads();
        sh[t] += x;
        __syncthreads();
    }
    int excl = sh[t] - s;
    if (t == 255) blocksum[b] = sh[255];
    int run = excl;
    for (int j = 0; j < 4; j++) {
        int idx = base + j;
        if (idx < Nn) offs[idx] = run;
        run += v[j];
    }
}

// fused scan2+scan3: per-thread prefix over <=G block sums (L2-hot)
__global__ void scan23(int* __restrict__ offs, const int* __restrict__ bsum,
                       int* __restrict__ cursor, int Nn, int G) {
    int i = blockIdx.x * 256 + threadIdx.x;
    if (i > Nn) return;
    int g = i >> 10;
    int basev = 0;
    for (int k = 0; k < g; k++) basev += bsum[k];
    if (i == Nn) {
        int tot = basev;
        for (int k = g; k < G; k++) tot += bsum[k];
        offs[Nn] = tot;
        return;
    }
    int v = offs[i] + basev;
    offs[i] = v;
    cursor[i] = v;
}

__global__ void fill_csr(const int* __restrict__ ei, int* cursor, int* csr, int E, int Nn) {
    int t = blockIdx.x * 256 + threadIdx.x;
    if (t < E) {
        int s = ei[t];
        int d = ei[E + t];
        int p = atomicAdd(&cursor[d], 1);
        csr[p] = s;
    } else if (t < E + Nn) {
        int nn = t - E;
        int p = atomicAdd(&cursor[nn], 1);
        csr[p] = nn;
    }
}

// ------- prep: all fp32->bf16 conversions + edge degree count (deg pre-zeroed) -------

__global__ __launch_bounds__(256) void prep_all(
    int* __restrict__ deg, const int* __restrict__ ei, int E,
    const float* __restrict__ x, unsigned short* __restrict__ xb, int nx, int nxpad,
    const float* __restrict__ w1, unsigned short* __restrict__ o1, int n1,
    const float* __restrict__ w2, unsigned short* __restrict__ o2, int n2,
    const float* __restrict__ w3, unsigned short* __restrict__ o3, int n3) {
    int id = blockIdx.x * 256 + threadIdx.x;
    int nconv = (nxpad + n1 + n2 + n3) / 8;
    if (id >= nconv) {
        int e = id - nconv;
        if (e < E) atomicAdd(&deg[ei[E + e]], 1);
        return;
    }
    int i = id * 8;
    const float* in;
    unsigned short* out;
    if (i < nxpad) {
        if (i >= nx) {
            *(ushort4*)&xb[i] = make_ushort4(0, 0, 0, 0);
            *(ushort4*)&xb[i + 4] = make_ushort4(0, 0, 0, 0);
            return;
        }
        in = x + i; out = xb + i;
    } else {
        int j = i - nxpad;
        if (j < n1) { in = w1 + j; out = o1 + j; }
        else if (j < n1 + n2) { in = w2 + (j - n1); out = o2 + (j - n1); }
        else { in = w3 + (j - n1 - n2); out = o3 + (j - n1 - n2); }
    }
    float4 a = *(const float4*)in;
    float4 b = *(const float4*)(in + 4);
    *(ushort4*)out = make_ushort4(f2bf(a.x), f2bf(a.y), f2bf(a.z), f2bf(a.w));
    *(ushort4*)(out + 4) = make_ushort4(f2bf(b.x), f2bf(b.y), f2bf(b.z), f2bf(b.w));
}

// ---------------- MFMA GEMM (TN) + fused attention-logit epilogue ----------------
// HEADS==4: flat grid gm*4, XCD-aware swizzle so the 4 head-blocks of one m-tile
// land on the same XCD (ids differing by 8 share an XCD under round-robin).

template <int K, int CO, int HEADS>
__global__ __launch_bounds__(256) void gemm_mfma(
    const unsigned short* __restrict__ Xb, const unsigned short* __restrict__ Wb,
    unsigned short* __restrict__ Hb, const float* __restrict__ a_s,
    const float* __restrict__ a_d, float* __restrict__ als, float* __restrict__ ald) {
    constexpr int BM = 128, BK = 64, LD = 72, SLD = 68;
    __shared__ __align__(16) char smem[4 * 32 * SLD * 4];
    unsigned short* As = (unsigned short*)smem;
    unsigned short* Bs = As + BM * LD;
    int tid = threadIdx.x;
    int wave = tid >> 6, lane = tid & 63;
    int quad = lane >> 4, l16 = lane & 15;
    int mt, hd;
    if (HEADS == 4) {
        int gm = gridDim.x >> 2;
        int gm8 = gm & ~7;
        int nfull = gm8 * 4;
        int id = blockIdx.x;
        if (id < nfull) {
            int r = id & 31;
            mt = (id >> 5) * 8 + (r & 7);
            hd = r >> 3;
        } else {
            int t2 = id - nfull;
            mt = gm8 + (t2 >> 2);
            hd = t2 & 3;
        }
    } else {
        mt = blockIdx.x;
        hd = 0;
    }
    int m0 = mt * BM, n0 = hd * 64;
    int arow = tid >> 3;
    int achk = (tid & 7) * 8;
    f32x4 acc[2][4] = {};
    for (int k0 = 0; k0 < K; k0 += BK) {
        __syncthreads();
#pragma unroll
        for (int p = 0; p < 4; p++) {
            int r = arow + p * 32;
            *(int4*)&As[r * LD + achk] = *(const int4*)&Xb[(size_t)(m0 + r) * K + k0 + achk];
        }
#pragma unroll
        for (int p = 0; p < 2; p++) {
            int r = arow + p * 32;
            *(int4*)&Bs[r * LD + achk] = *(const int4*)&Wb[(size_t)(n0 + r) * K + k0 + achk];
        }
        __syncthreads();
#pragma unroll
        for (int ks = 0; ks < 2; ks++) {
            short8 af[2], bfr[4];
#pragma unroll
            for (int i = 0; i < 2; i++)
                af[i] = *(const short8*)&As[(wave * 32 + i * 16 + l16) * LD + ks * 32 + quad * 8];
#pragma unroll
            for (int j = 0; j < 4; j++)
                bfr[j] = *(const short8*)&Bs[(j * 16 + l16) * LD + ks * 32 + quad * 8];
#pragma unroll
            for (int i = 0; i < 2; i++)
#pragma unroll
                for (int j = 0; j < 4; j++)
                    acc[i][j] = __builtin_amdgcn_mfma_f32_16x16x32_bf16(af[i], bfr[j], acc[i][j], 0, 0, 0);
        }
    }
    __syncthreads();

    float asv[4], adv[4];
#pragma unroll
    for (int j = 0; j < 4; j++) {
        asv[j] = a_s[hd * 64 + j * 16 + l16];
        adv[j] = a_d[hd * 64 + j * 16 + l16];
    }
#pragma unroll
    for (int i = 0; i < 2; i++)
#pragma unroll
        for (int r = 0; r < 4; r++) {
            float ps = acc[i][0][r] * asv[0] + acc[i][1][r] * asv[1] +
                       acc[i][2][r] * asv[2] + acc[i][3][r] * asv[3];
            float pd = acc[i][0][r] * adv[0] + acc[i][1][r] * adv[1] +
                       acc[i][2][r] * adv[2] + acc[i][3][r] * adv[3];
#pragma unroll
            for (int mm = 1; mm < 16; mm <<= 1) {
                ps += __shfl_xor(ps, mm);
                pd += __shfl_xor(pd, mm);
            }
            if (l16 == 0) {
                int m = m0 + wave * 32 + i * 16 + quad * 4 + r;
                als[m * HEADS + hd] = ps;
                ald[m * HEADS + hd] = pd;
            }
        }

    float* stg = (float*)smem + wave * 32 * SLD;
#pragma unroll
    for (int i = 0; i < 2; i++)
#pragma unroll
        for (int j = 0; j < 4; j++)
#pragma unroll
            for (int r = 0; r < 4; r++)
                stg[(i * 16 + quad * 4 + r) * SLD + j * 16 + l16] = acc[i][j][r];
    int g = lane >> 3, c8 = (lane & 7) * 8;
#pragma unroll
    for (int p = 0; p < 4; p++) {
        int row = p * 8 + g;
        float4 v0 = *(const float4*)&stg[row * SLD + c8];
        float4 v1 = *(const float4*)&stg[row * SLD + c8 + 4];
        uint4 o;
        o.x = ((unsigned)f2bf(v0.y) << 16) | f2bf(v0.x);
        o.y = ((unsigned)f2bf(v0.w) << 16) | f2bf(v0.z);
        o.z = ((unsigned)f2bf(v1.y) << 16) | f2bf(v1.x);
        o.w = ((unsigned)f2bf(v1.w) << 16) | f2bf(v1.z);
        *(uint4*)&Hb[(size_t)(m0 + wave * 32 + row) * CO + n0 + c8] = o;
    }
}

// ------- edge-softmax aggregation (inline w, unroll-8, bf16 out, fused BN stats) -----
// BN partial stats: LDS-reduce block's 4 nodes, then atomicAdd into one of 64
// coalesced 512-float copies (partial[(blockIdx&63)*512 + t]). partial pre-zeroed.

#define EDGE4(sA, sB, sC, sD)                                                        \
    {                                                                                \
        float a0 = als[(sA)*4 + hd], a1 = als[(sB)*4 + hd];                          \
        float a2 = als[(sC)*4 + hd], a3 = als[(sD)*4 + hd];                          \
        ushort4 h0 = *(const ushort4*)&Hb[(size_t)(sA)*256 + c4];                    \
        ushort4 h1 = *(const ushort4*)&Hb[(size_t)(sB)*256 + c4];                    \
        ushort4 h2 = *(const ushort4*)&Hb[(size_t)(sC)*256 + c4];                    \
        ushort4 h3 = *(const ushort4*)&Hb[(size_t)(sD)*256 + c4];                    \
        float e0 = a0 + aldn; e0 = e0 > 0.f ? e0 : NEG_ATT * e0;                     \
        float e1 = a1 + aldn; e1 = e1 > 0.f ? e1 : NEG_ATT * e1;                     \
        float e2 = a2 + aldn; e2 = e2 > 0.f ? e2 : NEG_ATT * e2;                     \
        float e3 = a3 + aldn; e3 = e3 > 0.f ? e3 : NEG_ATT * e3;                     \
        float w0 = __expf(e0), w1 = __expf(e1), w2 = __expf(e2), w3 = __expf(e3);    \
        den += (w0 + w1) + (w2 + w3);                                                \
        acc.x += w0 * b2f(h0.x) + w1 * b2f(h1.x) + w2 * b2f(h2.x) + w3 * b2f(h3.x);  \
        acc.y += w0 * b2f(h0.y) + w1 * b2f(h1.y) + w2 * b2f(h2.y) + w3 * b2f(h3.y);  \
        acc.z += w0 * b2f(h0.z) + w1 * b2f(h1.z) + w2 * b2f(h2.z) + w3 * b2f(h3.z);  \
        acc.w += w0 * b2f(h0.w) + w1 * b2f(h1.w) + w2 * b2f(h2.w) + w3 * b2f(h3.w);  \
    }

__global__ __launch_bounds__(256) void aggregate_h4(
    const unsigned short* __restrict__ Hb, const float* __restrict__ als,
    const float* __restrict__ ald, const int* __restrict__ offs,
    const int* __restrict__ csr, unsigned short* __restrict__ Yb,
    float* __restrict__ partial, int Nn) {
    __shared__ float red[4 * 512];
    int wave = threadIdx.x >> 6;
    int lane = threadIdx.x & 63;
    int n = blockIdx.x * 4 + wave;
    int hd = lane >> 4;
    int c4 = lane * 4;
    float4 o4 = make_float4(0.f, 0.f, 0.f, 0.f);
    if (n < Nn) {
        float aldn = ald[n * 4 + hd];
        int beg = offs[n], end = offs[n + 1];
        float4 acc = make_float4(0.f, 0.f, 0.f, 0.f);
        float den = 0.f;
        for (int b = beg; b < end; b += 64) {
            int cnt = min(64, end - b);
            int idx = 0;
            if (lane < cnt) idx = csr[b + lane];
            int j = 0;
            for (; j + 8 <= cnt; j += 8) {
                int s0 = __shfl(idx, j), s1 = __shfl(idx, j + 1);
                int s2 = __shfl(idx, j + 2), s3 = __shfl(idx, j + 3);
                int s4 = __shfl(idx, j + 4), s5 = __shfl(idx, j + 5);
                int s6 = __shfl(idx, j + 6), s7 = __shfl(idx, j + 7);
                EDGE4(s0, s1, s2, s3);
                EDGE4(s4, s5, s6, s7);
            }
            for (; j + 4 <= cnt; j += 4) {
                int s0 = __shfl(idx, j), s1 = __shfl(idx, j + 1);
                int s2 = __shfl(idx, j + 2), s3 = __shfl(idx, j + 3);
                EDGE4(s0, s1, s2, s3);
            }
            for (; j < cnt; j++) {
                int s = __shfl(idx, j);
                float e = als[s * 4 + hd] + aldn;
                e = e > 0.f ? e : NEG_ATT * e;
                float w = __expf(e);
                den += w;
                ushort4 hv = *(const ushort4*)&Hb[(size_t)s * 256 + c4];
                acc.x += w * b2f(hv.x); acc.y += w * b2f(hv.y);
                acc.z += w * b2f(hv.z); acc.w += w * b2f(hv.w);
            }
        }
        float inv = 1.f / den;
        o4 = make_float4(acc.x * inv, acc.y * inv, acc.z * inv, acc.w * inv);
        ushort4 ub = make_ushort4(f2bf(o4.x), f2bf(o4.y), f2bf(o4.z), f2bf(o4.w));
        *(ushort4*)&Yb[(size_t)n * 256 + c4] = ub;
        // stats on the bf16-rounded values (must match what bn_apply reads)
        o4 = make_float4(b2f(ub.x), b2f(ub.y), b2f(ub.z), b2f(ub.w));
    }
    // fused BN partial stats
    float* rs = &red[wave * 512];
    rs[c4 + 0] = o4.x; rs[c4 + 1] = o4.y; rs[c4 + 2] = o4.z; rs[c4 + 3] = o4.w;
    rs[256 + c4 + 0] = o4.x * o4.x; rs[256 + c4 + 1] = o4.y * o4.y;
    rs[256 + c4 + 2] = o4.z * o4.z; rs[256 + c4 + 3] = o4.w * o4.w;
    __syncthreads();
    int t = threadIdx.x;
    int copy = (blockIdx.x & 63) * 512;
    float v0 = red[t] + red[512 + t] + red[1024 + t] + red[1536 + t];
    float v1 = red[256 + t] + red[768 + t] + red[1280 + t] + red[1792 + t];
    atomicAdd(&partial[copy + t], v0);
    atomicAdd(&partial[copy + 256 + t], v1);
}

// heads=1: final layer, writes fp32 out (keeps bias).
__global__ __launch_bounds__(256) void aggregate_h1(
    const unsigned short* __restrict__ Hb, const float* __restrict__ als,
    const float* __restrict__ ald, const int* __restrict__ offs,
    const int* __restrict__ csr, const float* __restrict__ bias,
    float* __restrict__ Yout, int Nn) {
    int wave = threadIdx.x >> 6;
    int lane = threadIdx.x & 63;
    int sub = lane >> 4, lane16 = lane & 15;
    int n = blockIdx.x * 16 + wave * 4 + sub;
    if (n >= Nn) return;
    int c4 = lane16 * 4;
    float aldn = ald[n];
    int beg = offs[n], end = offs[n + 1];
    float4 acc = make_float4(0.f, 0.f, 0.f, 0.f);
    float den = 0.f;
    for (int b = beg; b < end; b += 16) {
        int cnt = min(16, end - b);
        int idx = 0;
        if (lane16 < cnt) idx = csr[b + lane16];
        int j = 0;
        for (; j + 4 <= cnt; j += 4) {
            int s0 = __shfl(idx, (sub << 4) + j);
            int s1 = __shfl(idx, (sub << 4) + j + 1);
            int s2 = __shfl(idx, (sub << 4) + j + 2);
            int s3 = __shfl(idx, (sub << 4) + j + 3);
            float a0 = als[s0], a1 = als[s1], a2 = als[s2], a3 = als[s3];
            ushort4 h0 = *(const ushort4*)&Hb[(size_t)s0 * 64 + c4];
            ushort4 h1 = *(const ushort4*)&Hb[(size_t)s1 * 64 + c4];
            ushort4 h2 = *(const ushort4*)&Hb[(size_t)s2 * 64 + c4];
            ushort4 h3 = *(const ushort4*)&Hb[(size_t)s3 * 64 + c4];
            float e0 = a0 + aldn; e0 = e0 > 0.f ? e0 : NEG_ATT * e0;
            float e1 = a1 + aldn; e1 = e1 > 0.f ? e1 : NEG_ATT * e1;
            float e2 = a2 + aldn; e2 = e2 > 0.f ? e2 : NEG_ATT * e2;
            float e3 = a3 + aldn; e3 = e3 > 0.f ? e3 : NEG_ATT * e3;
            float w0 = __expf(e0), w1 = __expf(e1), w2 = __expf(e2), w3 = __expf(e3);
            den += (w0 + w1) + (w2 + w3);
            acc.x += w0 * b2f(h0.x) + w1 * b2f(h1.x) + w2 * b2f(h2.x) + w3 * b2f(h3.x);
            acc.y += w0 * b2f(h0.y) + w1 * b2f(h1.y) + w2 * b2f(h2.y) + w3 * b2f(h3.y);
            acc.z += w0 * b2f(h0.z) + w1 * b2f(h1.z) + w2 * b2f(h2.z) + w3 * b2f(h3.z);
            acc.w += w0 * b2f(h0.w) + w1 * b2f(h1.w) + w2 * b2f(h2.w) + w3 * b2f(h3.w);
        }
        for (; j < cnt; j++) {
            int s = __shfl(idx, (sub << 4) + j);
            float e = als[s] + aldn;
            e = e > 0.f ? e : NEG_ATT * e;
            float w = __expf(e);
            den += w;
            ushort4 hv = *(const ushort4*)&Hb[(size_t)s * 64 + c4];
            acc.x += w * b2f(hv.x); acc.y += w * b2f(hv.y);
            acc.z += w * b2f(hv.z); acc.w += w * b2f(hv.w);
        }
    }
    float inv = 1.f / den;
    float4 bv = *(const float4*)&bias[c4];
    float4 o = make_float4(acc.x * inv + bv.x, acc.y * inv + bv.y,
                           acc.z * inv + bv.z, acc.w * inv + bv.w);
    *(float4*)&Yout[(size_t)n * 64 + c4] = o;
}

// ---------------- BN reduce (64 copies) + scale/shift ----------------

__global__ __launch_bounds__(256) void bn_reduce_final(
    const float* __restrict__ partial, const float* __restrict__ gamma,
    const float* __restrict__ beta, float* scale, float* shift, int Nn) {
    int ch = threadIdx.x;  // one thread per channel, one block total
    float s = 0.f, q = 0.f;
    for (int i = 0; i < 64; i++) {
        s += partial[i * 512 + ch];
        q += partial[i * 512 + 256 + ch];
    }
    float inv_n = 1.f / (float)Nn;
    float mu = s * inv_n;
    float var = q * inv_n - mu * mu;
    float sc = gamma[ch] * rsqrtf(var + 1e-5f);
    scale[ch] = sc;
    shift[ch] = beta[ch] - mu * sc;
}

// BN apply + leaky + optional residual from OutB's previous bf16 contents.
template <bool RES>
__global__ __launch_bounds__(256) void bn_apply(const unsigned short* __restrict__ Yb,
                                                const float* __restrict__ scale,
                                                const float* __restrict__ shift,
                                                unsigned short* __restrict__ OutB,
                                                int total4, int total4pad) {
    int i = blockIdx.x * 256 + threadIdx.x;
    if (i >= total4pad) return;
    if (i >= total4) {
        *(ushort4*)&OutB[i * 4] = make_ushort4(0, 0, 0, 0);
        return;
    }
    ushort4 u = *(const ushort4*)&Yb[i * 4];
    int cb = (i * 4) & 255;
    float4 sc = *(const float4*)&scale[cb];
    float4 sh = *(const float4*)&shift[cb];
    float4 o;
    o.x = sc.x * b2f(u.x) + sh.x; o.x = o.x > 0.f ? o.x : NEG_ACT * o.x;
    o.y = sc.y * b2f(u.y) + sh.y; o.y = o.y > 0.f ? o.y : NEG_ACT * o.y;
    o.z = sc.z * b2f(u.z) + sh.z; o.z = o.z > 0.f ? o.z : NEG_ACT * o.z;
    o.w = sc.w * b2f(u.w) + sh.w; o.w = o.w > 0.f ? o.w : NEG_ACT * o.w;
    if (RES) {
        ushort4 r = *(const ushort4*)&OutB[i * 4];
        o.x += b2f(r.x); o.y += b2f(r.y); o.z += b2f(r.z); o.w += b2f(r.w);
    }
    *(ushort4*)&OutB[i * 4] = make_ushort4(f2bf(o.x), f2bf(o.y), f2bf(o.z), f2bf(o.w));
}

// ---------------- launch ----------------

extern "C" void kernel_launch(void* const* d_in, const int* in_sizes, int n_in,
                              void* d_out, int out_size, void* d_ws, size_t ws_size,
                              hipStream_t stream) {
    const float* x    = (const float*)d_in[0];
    const int*   ei   = (const int*)d_in[1];
    const float* W1   = (const float*)d_in[2];
    const float* a1s  = (const float*)d_in[3];
    const float* a1d  = (const float*)d_in[4];
    const float* W2   = (const float*)d_in[6];
    const float* a2s  = (const float*)d_in[7];
    const float* a2d  = (const float*)d_in[8];
    const float* W3   = (const float*)d_in[10];
    const float* a3s  = (const float*)d_in[11];
    const float* a3d  = (const float*)d_in[12];
    const float* b3   = (const float*)d_in[13];
    const float* gamma = (const float*)d_in[14];
    const float* beta  = (const float*)d_in[15];
    float* out = (float*)d_out;

    const int Nn = in_sizes[0] / 128;
    const int E  = in_sizes[1] / 2;
    const int Ep = E + Nn;
    const int Mpad = (Nn + 127) & ~127;

    size_t off = 0;
    char* base = (char*)d_ws;
    auto alloc = [&](size_t bytes) -> void* {
        void* p = base + off;
        off = (off + bytes + 255) & ~(size_t)255;
        return p;
    };
    unsigned short* Hb   = (unsigned short*)alloc((size_t)Mpad * 256 * 2);
    unsigned short* Yb   = (unsigned short*)alloc((size_t)Nn * 256 * 2);
    unsigned short* xb1  = (unsigned short*)alloc((size_t)Mpad * 128 * 2);
    unsigned short* xbig = (unsigned short*)alloc((size_t)Mpad * 256 * 2);
    unsigned short* wb1  = (unsigned short*)alloc((size_t)256 * 128 * 2);
    unsigned short* wb2  = (unsigned short*)alloc((size_t)256 * 256 * 2);
    unsigned short* wb3  = (unsigned short*)alloc((size_t)64 * 256 * 2);
    float* als    = (float*)alloc((size_t)Mpad * 4 * 4);
    float* ald    = (float*)alloc((size_t)Mpad * 4 * 4);
    int*   deg    = (int*)alloc((size_t)Nn * 4);
    int*   offs   = (int*)alloc((size_t)(Nn + 1) * 4);
    int*   cursor = (int*)alloc((size_t)Nn * 4);
    int*   bsum   = (int*)alloc(64 * 4);
    int*   csr    = (int*)alloc((size_t)Ep * 4);
    float* partial = (float*)alloc(64 * 512 * 4);
    float* scale  = (float*)alloc(256 * 4);
    float* shift  = (float*)alloc(256 * 4);
    (void)ws_size;

    const int G = (Nn + SCAN_CHUNK - 1) / SCAN_CHUNK;

    // ---- deg zero + prep (conversions + edge counting) ----
    hipMemsetAsync(deg, 0, (size_t)Nn * 4, stream);
    {
        int nxpad = Mpad * 128;
        int wtot = 256 * 128 + 256 * 256 + 64 * 256;
        int nconv = (nxpad + wtot) / 8;
        prep_all<<<(nconv + E + 255) / 256, 256, 0, stream>>>(
            deg, ei, E, x, xb1, Nn * 128, nxpad,
            W1, wb1, 256 * 128, W2, wb2, 256 * 256, W3, wb3, 64 * 256);
    }

    // ---- CSR build ----
    scan1<<<G, 256, 0, stream>>>(deg, offs, bsum, Nn);
    scan23<<<(Nn + 1 + 255) / 256, 256, 0, stream>>>(offs, bsum, cursor, Nn, G);
    fill_csr<<<(Ep + 255) / 256, 256, 0, stream>>>(ei, cursor, csr, E, Nn);

    const int gm = Mpad / 128;
    const int nagg4 = (Nn + 3) / 4;
    const int nagg1 = (Nn + 15) / 16;
    const int total4 = Nn * 64;
    const int total4pad = Mpad * 64;
    const int napply = (total4pad + 255) / 256;

    // ---- Layer 1 ----
    gemm_mfma<128, 256, 4><<<gm * 4, 256, 0, stream>>>(xb1, wb1, Hb, a1s, a1d, als, ald);
    hipMemsetAsync(partial, 0, 64 * 512 * 4, stream);
    aggregate_h4<<<nagg4, 256, 0, stream>>>(Hb, als, ald, offs, csr, Yb, partial, Nn);
    bn_reduce_final<<<1, 256, 0, stream>>>(partial, gamma, beta, scale, shift, Nn);
    bn_apply<false><<<napply, 256, 0, stream>>>(Yb, scale, shift, xbig, total4, total4pad);

    // ---- Layer 2 (residual read from xbig's previous bf16 contents) ----
    gemm_mfma<256, 256, 4><<<gm * 4, 256, 0, stream>>>(xbig, wb2, Hb, a2s, a2d, als, ald);
    hipMemsetAsync(partial, 0, 64 * 512 * 4, stream);
    aggregate_h4<<<nagg4, 256, 0, stream>>>(Hb, als, ald, offs, csr, Yb, partial, Nn);
    bn_reduce_final<<<1, 256, 0, stream>>>(partial, gamma, beta, scale, shift, Nn);
    bn_apply<true><<<napply, 256, 0, stream>>>(Yb, scale, shift, xbig, total4, total4pad);

    // ---- Layer 3 ----
    gemm_mfma<256, 64, 1><<<gm, 256, 0, stream>>>(xbig, wb3, Hb, a3s, a3d, als, ald);
    aggregate_h1<<<nagg1, 256, 0, stream>>>(Hb, als, ald, offs, csr, b3, out, Nn);
}

// Round 12
// 326.008 us; speedup vs baseline: 1.0255x; 1.0255x over previous
//
#include <hip/hip_runtime.h>
#include <hip/hip_bf16.h>

#define NEG_ATT 0.2f
#define NEG_ACT 0.01f

typedef __attribute__((ext_vector_type(8))) short short8;
typedef __attribute__((ext_vector_type(4))) float f32x4;

__device__ __forceinline__ unsigned short f2bf(float f) {
    unsigned int u = __float_as_uint(f);
    unsigned int r = (u + 0x7fff + ((u >> 16) & 1)) >> 16;  // RNE
    return (unsigned short)r;
}
__device__ __forceinline__ float b2f(unsigned short h) {
    return __uint_as_float((unsigned int)h << 16);
}

// ---------------- CSR build ----------------

#define SCAN_CHUNK 1024
// deg holds edge-counts only (self-loop added as +1 here)
__global__ void scan1(const int* __restrict__ deg, int* __restrict__ offs,
                      int* blocksum, int Nn) {
    __shared__ int sh[256];
    int b = blockIdx.x, t = threadIdx.x;
    int base = b * SCAN_CHUNK + t * 4;
    int v[4];
    int s = 0;
    for (int j = 0; j < 4; j++) {
        int idx = base + j;
        v[j] = (idx < Nn) ? deg[idx] + 1 : 0;
        s += v[j];
    }
    sh[t] = s;
    __syncthreads();
    for (int off = 1; off < 256; off <<= 1) {
        int x = (t >= off) ? sh[t - off] : 0;
        __syncthreads();
        sh[t] += x;
        __syncthreads();
    }
    int excl = sh[t] - s;
    if (t == 255) blocksum[b] = sh[255];
    int run = excl;
    for (int j = 0; j < 4; j++) {
        int idx = base + j;
        if (idx < Nn) offs[idx] = run;
        run += v[j];
    }
}

// fused scan2+scan3: per-thread prefix over <=G block sums (L2-hot)
__global__ void scan23(int* __restrict__ offs, const int* __restrict__ bsum,
                       int* __restrict__ cursor, int Nn, int G) {
    int i = blockIdx.x * 256 + threadIdx.x;
    if (i > Nn) return;
    int g = i >> 10;
    int basev = 0;
    for (int k = 0; k < g; k++) basev += bsum[k];
    if (i == Nn) {
        int tot = basev;
        for (int k = g; k < G; k++) tot += bsum[k];
        offs[Nn] = tot;
        return;
    }
    int v = offs[i] + basev;
    offs[i] = v;
    cursor[i] = v;
}

__global__ void fill_csr(const int* __restrict__ ei, int* cursor, int* csr, int E, int Nn) {
    int t = blockIdx.x * 256 + threadIdx.x;
    if (t < E) {
        int s = ei[t];
        int d = ei[E + t];
        int p = atomicAdd(&cursor[d], 1);
        csr[p] = s;
    } else if (t < E + Nn) {
        int nn = t - E;
        int p = atomicAdd(&cursor[nn], 1);
        csr[p] = nn;
    }
}

// ------- prep: all fp32->bf16 conversions + edge degree count (deg pre-zeroed) -------

__global__ __launch_bounds__(256) void prep_all(
    int* __restrict__ deg, const int* __restrict__ ei, int E,
    const float* __restrict__ x, unsigned short* __restrict__ xb, int nx, int nxpad,
    const float* __restrict__ w1, unsigned short* __restrict__ o1, int n1,
    const float* __restrict__ w2, unsigned short* __restrict__ o2, int n2,
    const float* __restrict__ w3, unsigned short* __restrict__ o3, int n3) {
    int id = blockIdx.x * 256 + threadIdx.x;
    int nconv = (nxpad + n1 + n2 + n3) / 8;
    if (id >= nconv) {
        int e = id - nconv;
        if (e < E) atomicAdd(&deg[ei[E + e]], 1);
        return;
    }
    int i = id * 8;
    const float* in;
    unsigned short* out;
    if (i < nxpad) {
        if (i >= nx) {
            *(ushort4*)&xb[i] = make_ushort4(0, 0, 0, 0);
            *(ushort4*)&xb[i + 4] = make_ushort4(0, 0, 0, 0);
            return;
        }
        in = x + i; out = xb + i;
    } else {
        int j = i - nxpad;
        if (j < n1) { in = w1 + j; out = o1 + j; }
        else if (j < n1 + n2) { in = w2 + (j - n1); out = o2 + (j - n1); }
        else { in = w3 + (j - n1 - n2); out = o3 + (j - n1 - n2); }
    }
    float4 a = *(const float4*)in;
    float4 b = *(const float4*)(in + 4);
    *(ushort4*)out = make_ushort4(f2bf(a.x), f2bf(a.y), f2bf(a.z), f2bf(a.w));
    *(ushort4*)(out + 4) = make_ushort4(f2bf(b.x), f2bf(b.y), f2bf(b.z), f2bf(b.w));
}

// BN-apply transform for the fused gemm3 A-stage: leaky(sc*y+sh) + res, pack 2 bf16
__device__ __forceinline__ unsigned bnpack2(unsigned short ya, unsigned short yb_,
                                            float sca, float scb, float sha, float shb,
                                            unsigned short ra, unsigned short rb_) {
    float v0 = sca * b2f(ya) + sha; v0 = v0 > 0.f ? v0 : NEG_ACT * v0; v0 += b2f(ra);
    float v1 = scb * b2f(yb_) + shb; v1 = v1 > 0.f ? v1 : NEG_ACT * v1; v1 += b2f(rb_);
    return ((unsigned)f2bf(v1) << 16) | f2bf(v0);
}

// ---------------- MFMA GEMM (TN) + fused attention-logit epilogue ----------------
// HEADS==4: flat grid gm*4, XCD-aware swizzle so the 4 head-blocks of one m-tile
// land on the same XCD (ids differing by 8 share an XCD under round-robin).
// FUSE: A = leaky(scale*Yb_in+shift) + Res_in  (BN-apply fused into staging;
// only valid when each A row is staged once, i.e. HEADS==1).

template <int K, int CO, int HEADS, bool FUSE>
__global__ __launch_bounds__(256) void gemm_mfma(
    const unsigned short* __restrict__ Xb, const unsigned short* __restrict__ Wb,
    unsigned short* __restrict__ Hb, const float* __restrict__ a_s,
    const float* __restrict__ a_d, float* __restrict__ als, float* __restrict__ ald,
    const unsigned short* __restrict__ Yb_in, const unsigned short* __restrict__ Res_in,
    const float* __restrict__ scale, const float* __restrict__ shift, int Nn) {
    constexpr int BM = 128, BK = 64, LD = 72, SLD = 68;
    __shared__ __align__(16) char smem[4 * 32 * SLD * 4];
    unsigned short* As = (unsigned short*)smem;
    unsigned short* Bs = As + BM * LD;
    int tid = threadIdx.x;
    int wave = tid >> 6, lane = tid & 63;
    int quad = lane >> 4, l16 = lane & 15;
    int mt, hd;
    if (HEADS == 4) {
        int gm = gridDim.x >> 2;
        int gm8 = gm & ~7;
        int nfull = gm8 * 4;
        int id = blockIdx.x;
        if (id < nfull) {
            int r = id & 31;
            mt = (id >> 5) * 8 + (r & 7);
            hd = r >> 3;
        } else {
            int t2 = id - nfull;
            mt = gm8 + (t2 >> 2);
            hd = t2 & 3;
        }
    } else {
        mt = blockIdx.x;
        hd = 0;
    }
    int m0 = mt * BM, n0 = hd * 64;
    int arow = tid >> 3;
    int achk = (tid & 7) * 8;
    f32x4 acc[2][4] = {};
    for (int k0 = 0; k0 < K; k0 += BK) {
        __syncthreads();
        if (FUSE) {
            int cb = k0 + achk;
            float4 sc0 = *(const float4*)&scale[cb];
            float4 sc1 = *(const float4*)&scale[cb + 4];
            float4 sh0 = *(const float4*)&shift[cb];
            float4 sh1 = *(const float4*)&shift[cb + 4];
#pragma unroll
            for (int p = 0; p < 4; p++) {
                int r = arow + p * 32;
                int m = m0 + r;
                uint4 o = make_uint4(0, 0, 0, 0);
                if (m < Nn) {
                    ushort4 ua = *(const ushort4*)&Yb_in[(size_t)m * 256 + cb];
                    ushort4 ub = *(const ushort4*)&Yb_in[(size_t)m * 256 + cb + 4];
                    ushort4 ra = *(const ushort4*)&Res_in[(size_t)m * 256 + cb];
                    ushort4 rb = *(const ushort4*)&Res_in[(size_t)m * 256 + cb + 4];
                    o.x = bnpack2(ua.x, ua.y, sc0.x, sc0.y, sh0.x, sh0.y, ra.x, ra.y);
                    o.y = bnpack2(ua.z, ua.w, sc0.z, sc0.w, sh0.z, sh0.w, ra.z, ra.w);
                    o.z = bnpack2(ub.x, ub.y, sc1.x, sc1.y, sh1.x, sh1.y, rb.x, rb.y);
                    o.w = bnpack2(ub.z, ub.w, sc1.z, sc1.w, sh1.z, sh1.w, rb.z, rb.w);
                }
                *(uint4*)&As[r * LD + achk] = o;
            }
        } else {
#pragma unroll
            for (int p = 0; p < 4; p++) {
                int r = arow + p * 32;
                *(int4*)&As[r * LD + achk] = *(const int4*)&Xb[(size_t)(m0 + r) * K + k0 + achk];
            }
        }
#pragma unroll
        for (int p = 0; p < 2; p++) {
            int r = arow + p * 32;
            *(int4*)&Bs[r * LD + achk] = *(const int4*)&Wb[(size_t)(n0 + r) * K + k0 + achk];
        }
        __syncthreads();
#pragma unroll
        for (int ks = 0; ks < 2; ks++) {
            short8 af[2], bfr[4];
#pragma unroll
            for (int i = 0; i < 2; i++)
                af[i] = *(const short8*)&As[(wave * 32 + i * 16 + l16) * LD + ks * 32 + quad * 8];
#pragma unroll
            for (int j = 0; j < 4; j++)
                bfr[j] = *(const short8*)&Bs[(j * 16 + l16) * LD + ks * 32 + quad * 8];
#pragma unroll
            for (int i = 0; i < 2; i++)
#pragma unroll
                for (int j = 0; j < 4; j++)
                    acc[i][j] = __builtin_amdgcn_mfma_f32_16x16x32_bf16(af[i], bfr[j], acc[i][j], 0, 0, 0);
        }
    }
    __syncthreads();

    float asv[4], adv[4];
#pragma unroll
    for (int j = 0; j < 4; j++) {
        asv[j] = a_s[hd * 64 + j * 16 + l16];
        adv[j] = a_d[hd * 64 + j * 16 + l16];
    }
#pragma unroll
    for (int i = 0; i < 2; i++)
#pragma unroll
        for (int r = 0; r < 4; r++) {
            float ps = acc[i][0][r] * asv[0] + acc[i][1][r] * asv[1] +
                       acc[i][2][r] * asv[2] + acc[i][3][r] * asv[3];
            float pd = acc[i][0][r] * adv[0] + acc[i][1][r] * adv[1] +
                       acc[i][2][r] * adv[2] + acc[i][3][r] * adv[3];
#pragma unroll
            for (int mm = 1; mm < 16; mm <<= 1) {
                ps += __shfl_xor(ps, mm);
                pd += __shfl_xor(pd, mm);
            }
            if (l16 == 0) {
                int m = m0 + wave * 32 + i * 16 + quad * 4 + r;
                als[m * HEADS + hd] = ps;
                ald[m * HEADS + hd] = pd;
            }
        }

    float* stg = (float*)smem + wave * 32 * SLD;
#pragma unroll
    for (int i = 0; i < 2; i++)
#pragma unroll
        for (int j = 0; j < 4; j++)
#pragma unroll
            for (int r = 0; r < 4; r++)
                stg[(i * 16 + quad * 4 + r) * SLD + j * 16 + l16] = acc[i][j][r];
    int g = lane >> 3, c8 = (lane & 7) * 8;
#pragma unroll
    for (int p = 0; p < 4; p++) {
        int row = p * 8 + g;
        float4 v0 = *(const float4*)&stg[row * SLD + c8];
        float4 v1 = *(const float4*)&stg[row * SLD + c8 + 4];
        uint4 o;
        o.x = ((unsigned)f2bf(v0.y) << 16) | f2bf(v0.x);
        o.y = ((unsigned)f2bf(v0.w) << 16) | f2bf(v0.z);
        o.z = ((unsigned)f2bf(v1.y) << 16) | f2bf(v1.x);
        o.w = ((unsigned)f2bf(v1.w) << 16) | f2bf(v1.z);
        *(uint4*)&Hb[(size_t)(m0 + wave * 32 + row) * CO + n0 + c8] = o;
    }
}

// ---------------- edge-softmax aggregation (inline w, unroll-8, bf16 out) --------
// Round-10 version: no block barrier, no fused stats (r11 showed the barrier costs
// more than the separate bn_stats pass).

#define EDGE4(sA, sB, sC, sD)                                                        \
    {                                                                                \
        float a0 = als[(sA)*4 + hd], a1 = als[(sB)*4 + hd];                          \
        float a2 = als[(sC)*4 + hd], a3 = als[(sD)*4 + hd];                          \
        ushort4 h0 = *(const ushort4*)&Hb[(size_t)(sA)*256 + c4];                    \
        ushort4 h1 = *(const ushort4*)&Hb[(size_t)(sB)*256 + c4];                    \
        ushort4 h2 = *(const ushort4*)&Hb[(size_t)(sC)*256 + c4];                    \
        ushort4 h3 = *(const ushort4*)&Hb[(size_t)(sD)*256 + c4];                    \
        float e0 = a0 + aldn; e0 = e0 > 0.f ? e0 : NEG_ATT * e0;                     \
        float e1 = a1 + aldn; e1 = e1 > 0.f ? e1 : NEG_ATT * e1;                     \
        float e2 = a2 + aldn; e2 = e2 > 0.f ? e2 : NEG_ATT * e2;                     \
        float e3 = a3 + aldn; e3 = e3 > 0.f ? e3 : NEG_ATT * e3;                     \
        float w0 = __expf(e0), w1 = __expf(e1), w2 = __expf(e2), w3 = __expf(e3);    \
        den += (w0 + w1) + (w2 + w3);                                                \
        acc.x += w0 * b2f(h0.x) + w1 * b2f(h1.x) + w2 * b2f(h2.x) + w3 * b2f(h3.x);  \
        acc.y += w0 * b2f(h0.y) + w1 * b2f(h1.y) + w2 * b2f(h2.y) + w3 * b2f(h3.y);  \
        acc.z += w0 * b2f(h0.z) + w1 * b2f(h1.z) + w2 * b2f(h2.z) + w3 * b2f(h3.z);  \
        acc.w += w0 * b2f(h0.w) + w1 * b2f(h1.w) + w2 * b2f(h2.w) + w3 * b2f(h3.w);  \
    }

__global__ __launch_bounds__(256) void aggregate_h4(
    const unsigned short* __restrict__ Hb, const float* __restrict__ als,
    const float* __restrict__ ald, const int* __restrict__ offs,
    const int* __restrict__ csr, unsigned short* __restrict__ Yb, int Nn) {
    int wave = threadIdx.x >> 6;
    int lane = threadIdx.x & 63;
    int n = blockIdx.x * 4 + wave;
    if (n >= Nn) return;
    int hd = lane >> 4;
    int c4 = lane * 4;
    float aldn = ald[n * 4 + hd];
    int beg = offs[n], end = offs[n + 1];
    float4 acc = make_float4(0.f, 0.f, 0.f, 0.f);
    float den = 0.f;
    for (int b = beg; b < end; b += 64) {
        int cnt = min(64, end - b);
        int idx = 0;
        if (lane < cnt) idx = csr[b + lane];
        int j = 0;
        for (; j + 8 <= cnt; j += 8) {
            int s0 = __shfl(idx, j), s1 = __shfl(idx, j + 1);
            int s2 = __shfl(idx, j + 2), s3 = __shfl(idx, j + 3);
            int s4 = __shfl(idx, j + 4), s5 = __shfl(idx, j + 5);
            int s6 = __shfl(idx, j + 6), s7 = __shfl(idx, j + 7);
            EDGE4(s0, s1, s2, s3);
            EDGE4(s4, s5, s6, s7);
        }
        for (; j + 4 <= cnt; j += 4) {
            int s0 = __shfl(idx, j), s1 = __shfl(idx, j + 1);
            int s2 = __shfl(idx, j + 2), s3 = __shfl(idx, j + 3);
            EDGE4(s0, s1, s2, s3);
        }
        for (; j < cnt; j++) {
            int s = __shfl(idx, j);
            float e = als[s * 4 + hd] + aldn;
            e = e > 0.f ? e : NEG_ATT * e;
            float w = __expf(e);
            den += w;
            ushort4 hv = *(const ushort4*)&Hb[(size_t)s * 256 + c4];
            acc.x += w * b2f(hv.x); acc.y += w * b2f(hv.y);
            acc.z += w * b2f(hv.z); acc.w += w * b2f(hv.w);
        }
    }
    float inv = 1.f / den;
    *(ushort4*)&Yb[(size_t)n * 256 + c4] = make_ushort4(
        f2bf(acc.x * inv), f2bf(acc.y * inv), f2bf(acc.z * inv), f2bf(acc.w * inv));
}

// heads=1: final layer, writes fp32 out (keeps bias).
__global__ __launch_bounds__(256) void aggregate_h1(
    const unsigned short* __restrict__ Hb, const float* __restrict__ als,
    const float* __restrict__ ald, const int* __restrict__ offs,
    const int* __restrict__ csr, const float* __restrict__ bias,
    float* __restrict__ Yout, int Nn) {
    int wave = threadIdx.x >> 6;
    int lane = threadIdx.x & 63;
    int sub = lane >> 4, lane16 = lane & 15;
    int n = blockIdx.x * 16 + wave * 4 + sub;
    if (n >= Nn) return;
    int c4 = lane16 * 4;
    float aldn = ald[n];
    int beg = offs[n], end = offs[n + 1];
    float4 acc = make_float4(0.f, 0.f, 0.f, 0.f);
    float den = 0.f;
    for (int b = beg; b < end; b += 16) {
        int cnt = min(16, end - b);
        int idx = 0;
        if (lane16 < cnt) idx = csr[b + lane16];
        int j = 0;
        for (; j + 4 <= cnt; j += 4) {
            int s0 = __shfl(idx, (sub << 4) + j);
            int s1 = __shfl(idx, (sub << 4) + j + 1);
            int s2 = __shfl(idx, (sub << 4) + j + 2);
            int s3 = __shfl(idx, (sub << 4) + j + 3);
            float a0 = als[s0], a1 = als[s1], a2 = als[s2], a3 = als[s3];
            ushort4 h0 = *(const ushort4*)&Hb[(size_t)s0 * 64 + c4];
            ushort4 h1 = *(const ushort4*)&Hb[(size_t)s1 * 64 + c4];
            ushort4 h2 = *(const ushort4*)&Hb[(size_t)s2 * 64 + c4];
            ushort4 h3 = *(const ushort4*)&Hb[(size_t)s3 * 64 + c4];
            float e0 = a0 + aldn; e0 = e0 > 0.f ? e0 : NEG_ATT * e0;
            float e1 = a1 + aldn; e1 = e1 > 0.f ? e1 : NEG_ATT * e1;
            float e2 = a2 + aldn; e2 = e2 > 0.f ? e2 : NEG_ATT * e2;
            float e3 = a3 + aldn; e3 = e3 > 0.f ? e3 : NEG_ATT * e3;
            float w0 = __expf(e0), w1 = __expf(e1), w2 = __expf(e2), w3 = __expf(e3);
            den += (w0 + w1) + (w2 + w3);
            acc.x += w0 * b2f(h0.x) + w1 * b2f(h1.x) + w2 * b2f(h2.x) + w3 * b2f(h3.x);
            acc.y += w0 * b2f(h0.y) + w1 * b2f(h1.y) + w2 * b2f(h2.y) + w3 * b2f(h3.y);
            acc.z += w0 * b2f(h0.z) + w1 * b2f(h1.z) + w2 * b2f(h2.z) + w3 * b2f(h3.z);
            acc.w += w0 * b2f(h0.w) + w1 * b2f(h1.w) + w2 * b2f(h2.w) + w3 * b2f(h3.w);
        }
        for (; j < cnt; j++) {
            int s = __shfl(idx, (sub << 4) + j);
            float e = als[s] + aldn;
            e = e > 0.f ? e : NEG_ATT * e;
            float w = __expf(e);
            den += w;
            ushort4 hv = *(const ushort4*)&Hb[(size_t)s * 64 + c4];
            acc.x += w * b2f(hv.x); acc.y += w * b2f(hv.y);
            acc.z += w * b2f(hv.z); acc.w += w * b2f(hv.w);
        }
    }
    float inv = 1.f / den;
    float4 bv = *(const float4*)&bias[c4];
    float4 o = make_float4(acc.x * inv + bv.x, acc.y * inv + bv.y,
                           acc.z * inv + bv.z, acc.w * inv + bv.w);
    *(float4*)&Yout[(size_t)n * 64 + c4] = o;
}

// ---------------- BatchNorm stats over bf16 y (coalesced, 1024 blocks) ----------------

__global__ __launch_bounds__(256) void bn_stats(const unsigned short* __restrict__ Yb,
                                                float* __restrict__ partial, int Nn) {
    __shared__ float red[4 * 512];
    int t = threadIdx.x;
    int g = blockIdx.x;
    int rows_per = (Nn + gridDim.x - 1) / gridDim.x;
    int r0 = g * rows_per;
    int r1 = min(r0 + rows_per, Nn);
    int sub = t >> 6;
    int c4 = (t & 63) * 4;
    float4 s = make_float4(0.f, 0.f, 0.f, 0.f);
    float4 q = make_float4(0.f, 0.f, 0.f, 0.f);
    for (int r = r0 + sub; r < r1; r += 4) {
        ushort4 u = *(const ushort4*)&Yb[(size_t)r * 256 + c4];
        float vx = b2f(u.x), vy = b2f(u.y), vz = b2f(u.z), vw = b2f(u.w);
        s.x += vx; s.y += vy; s.z += vz; s.w += vw;
        q.x += vx * vx; q.y += vy * vy; q.z += vz * vz; q.w += vw * vw;
    }
    float* rs = &red[sub * 512];
    rs[c4 + 0] = s.x; rs[c4 + 1] = s.y; rs[c4 + 2] = s.z; rs[c4 + 3] = s.w;
    rs[256 + c4 + 0] = q.x; rs[256 + c4 + 1] = q.y;
    rs[256 + c4 + 2] = q.z; rs[256 + c4 + 3] = q.w;
    __syncthreads();
    float v0 = red[t] + red[512 + t] + red[1024 + t] + red[1536 + t];
    float v1 = red[256 + t] + red[768 + t] + red[1280 + t] + red[1792 + t];
    partial[(size_t)g * 512 + t] = v0;
    partial[(size_t)g * 512 + 256 + t] = v1;
}

__global__ __launch_bounds__(256) void bn_reduce_final(
    const float* __restrict__ partial, int NP, const float* __restrict__ gamma,
    const float* __restrict__ beta, float* scale, float* shift, int Nn) {
    __shared__ float sh[8];
    int ch = blockIdx.x;
    int t = threadIdx.x;
    int wave = t >> 6, lane = t & 63;
    float s = 0.f, q = 0.f;
    for (int i = t; i < NP; i += 256) {
        s += partial[(size_t)i * 512 + ch];
        q += partial[(size_t)i * 512 + 256 + ch];
    }
    for (int off = 32; off; off >>= 1) {
        s += __shfl_down(s, off);
        q += __shfl_down(q, off);
    }
    if (lane == 0) { sh[wave] = s; sh[4 + wave] = q; }
    __syncthreads();
    if (t == 0) {
        s = sh[0] + sh[1] + sh[2] + sh[3];
        q = sh[4] + sh[5] + sh[6] + sh[7];
        float inv_n = 1.f / (float)Nn;
        float mu = s * inv_n;
        float var = q * inv_n - mu * mu;
        float sc = gamma[ch] * rsqrtf(var + 1e-5f);
        scale[ch] = sc;
        shift[ch] = beta[ch] - mu * sc;
    }
}

// BN apply + leaky (layer 1 only now); writes bf16 OutB (layer-2 GEMM input).
__global__ __launch_bounds__(256) void bn_apply(const unsigned short* __restrict__ Yb,
                                                const float* __restrict__ scale,
                                                const float* __restrict__ shift,
                                                unsigned short* __restrict__ OutB,
                                                int total4, int total4pad) {
    int i = blockIdx.x * 256 + threadIdx.x;
    if (i >= total4pad) return;
    if (i >= total4) {
        *(ushort4*)&OutB[i * 4] = make_ushort4(0, 0, 0, 0);
        return;
    }
    ushort4 u = *(const ushort4*)&Yb[i * 4];
    int cb = (i * 4) & 255;
    float4 sc = *(const float4*)&scale[cb];
    float4 sh = *(const float4*)&shift[cb];
    float4 o;
    o.x = sc.x * b2f(u.x) + sh.x; o.x = o.x > 0.f ? o.x : NEG_ACT * o.x;
    o.y = sc.y * b2f(u.y) + sh.y; o.y = o.y > 0.f ? o.y : NEG_ACT * o.y;
    o.z = sc.z * b2f(u.z) + sh.z; o.z = o.z > 0.f ? o.z : NEG_ACT * o.z;
    o.w = sc.w * b2f(u.w) + sh.w; o.w = o.w > 0.f ? o.w : NEG_ACT * o.w;
    *(ushort4*)&OutB[i * 4] = make_ushort4(f2bf(o.x), f2bf(o.y), f2bf(o.z), f2bf(o.w));
}

// ---------------- launch ----------------

extern "C" void kernel_launch(void* const* d_in, const int* in_sizes, int n_in,
                              void* d_out, int out_size, void* d_ws, size_t ws_size,
                              hipStream_t stream) {
    const float* x    = (const float*)d_in[0];
    const int*   ei   = (const int*)d_in[1];
    const float* W1   = (const float*)d_in[2];
    const float* a1s  = (const float*)d_in[3];
    const float* a1d  = (const float*)d_in[4];
    const float* W2   = (const float*)d_in[6];
    const float* a2s  = (const float*)d_in[7];
    const float* a2d  = (const float*)d_in[8];
    const float* W3   = (const float*)d_in[10];
    const float* a3s  = (const float*)d_in[11];
    const float* a3d  = (const float*)d_in[12];
    const float* b3   = (const float*)d_in[13];
    const float* gamma = (const float*)d_in[14];
    const float* beta  = (const float*)d_in[15];
    float* out = (float*)d_out;

    const int Nn = in_sizes[0] / 128;
    const int E  = in_sizes[1] / 2;
    const int Ep = E + Nn;
    const int Mpad = (Nn + 127) & ~127;

    size_t off = 0;
    char* base = (char*)d_ws;
    auto alloc = [&](size_t bytes) -> void* {
        void* p = base + off;
        off = (off + bytes + 255) & ~(size_t)255;
        return p;
    };
    unsigned short* Hb   = (unsigned short*)alloc((size_t)Mpad * 256 * 2);
    unsigned short* Yb   = (unsigned short*)alloc((size_t)Nn * 256 * 2);
    unsigned short* xb1  = (unsigned short*)alloc((size_t)Mpad * 128 * 2);
    unsigned short* xbig = (unsigned short*)alloc((size_t)Mpad * 256 * 2);
    unsigned short* wb1  = (unsigned short*)alloc((size_t)256 * 128 * 2);
    unsigned short* wb2  = (unsigned short*)alloc((size_t)256 * 256 * 2);
    unsigned short* wb3  = (unsigned short*)alloc((size_t)64 * 256 * 2);
    float* als    = (float*)alloc((size_t)Mpad * 4 * 4);
    float* ald    = (float*)alloc((size_t)Mpad * 4 * 4);
    int*   deg    = (int*)alloc((size_t)Nn * 4);
    int*   offs   = (int*)alloc((size_t)(Nn + 1) * 4);
    int*   cursor = (int*)alloc((size_t)Nn * 4);
    int*   bsum   = (int*)alloc(64 * 4);
    int*   csr    = (int*)alloc((size_t)Ep * 4);
    const int NP = 1024;
    float* partial = (float*)alloc((size_t)NP * 512 * 4);
    float* scale  = (float*)alloc(256 * 4);
    float* shift  = (float*)alloc(256 * 4);
    (void)ws_size;

    const int G = (Nn + SCAN_CHUNK - 1) / SCAN_CHUNK;

    // ---- deg zero + prep (conversions + edge counting) ----
    hipMemsetAsync(deg, 0, (size_t)Nn * 4, stream);
    {
        int nxpad = Mpad * 128;
        int wtot = 256 * 128 + 256 * 256 + 64 * 256;
        int nconv = (nxpad + wtot) / 8;
        prep_all<<<(nconv + E + 255) / 256, 256, 0, stream>>>(
            deg, ei, E, x, xb1, Nn * 128, nxpad,
            W1, wb1, 256 * 128, W2, wb2, 256 * 256, W3, wb3, 64 * 256);
    }

    // ---- CSR build ----
    scan1<<<G, 256, 0, stream>>>(deg, offs, bsum, Nn);
    scan23<<<(Nn + 1 + 255) / 256, 256, 0, stream>>>(offs, bsum, cursor, Nn, G);
    fill_csr<<<(Ep + 255) / 256, 256, 0, stream>>>(ei, cursor, csr, E, Nn);

    const int gm = Mpad / 128;
    const int nagg4 = (Nn + 3) / 4;
    const int nagg1 = (Nn + 15) / 16;
    const int total4 = Nn * 64;
    const int total4pad = Mpad * 64;
    const int napply = (total4pad + 255) / 256;

    // ---- Layer 1 ----
    gemm_mfma<128, 256, 4, false><<<gm * 4, 256, 0, stream>>>(
        xb1, wb1, Hb, a1s, a1d, als, ald, nullptr, nullptr, nullptr, nullptr, 0);
    aggregate_h4<<<nagg4, 256, 0, stream>>>(Hb, als, ald, offs, csr, Yb, Nn);
    bn_stats<<<NP, 256, 0, stream>>>(Yb, partial, Nn);
    bn_reduce_final<<<256, 256, 0, stream>>>(partial, NP, gamma, beta, scale, shift, Nn);
    bn_apply<<<napply, 256, 0, stream>>>(Yb, scale, shift, xbig, total4, total4pad);

    // ---- Layer 2 ----
    gemm_mfma<256, 256, 4, false><<<gm * 4, 256, 0, stream>>>(
        xbig, wb2, Hb, a2s, a2d, als, ald, nullptr, nullptr, nullptr, nullptr, 0);
    aggregate_h4<<<nagg4, 256, 0, stream>>>(Hb, als, ald, offs, csr, Yb, Nn);
    bn_stats<<<NP, 256, 0, stream>>>(Yb, partial, Nn);
    bn_reduce_final<<<256, 256, 0, stream>>>(partial, NP, gamma, beta, scale, shift, Nn);

    // ---- Layer 3 (BN-apply of layer-2 + residual fused into A-staging) ----
    gemm_mfma<256, 64, 1, true><<<gm, 256, 0, stream>>>(
        nullptr, wb3, Hb, a3s, a3d, als, ald, Yb, xbig, scale, shift, Nn);
    aggregate_h1<<<nagg1, 256, 0, stream>>>(Hb, als, ald, offs, csr, b3, out, Nn);
}

// Round 13
// 324.192 us; speedup vs baseline: 1.0312x; 1.0056x over previous
//
#include <hip/hip_runtime.h>
#include <hip/hip_bf16.h>

#define NEG_ATT 0.2f
#define NEG_ACT 0.01f

typedef __attribute__((ext_vector_type(8))) short short8;
typedef __attribute__((ext_vector_type(4))) float f32x4;

__device__ __forceinline__ unsigned short f2bf(float f) {
    unsigned int u = __float_as_uint(f);
    unsigned int r = (u + 0x7fff + ((u >> 16) & 1)) >> 16;  // RNE
    return (unsigned short)r;
}
__device__ __forceinline__ float b2f(unsigned short h) {
    return __uint_as_float((unsigned int)h << 16);
}

// ---------------- CSR build ----------------

#define SCAN_CHUNK 1024
// deg holds edge-counts only (self-loop added as +1 here)
__global__ void scan1(const int* __restrict__ deg, int* __restrict__ offs,
                      int* blocksum, int Nn) {
    __shared__ int sh[256];
    int b = blockIdx.x, t = threadIdx.x;
    int base = b * SCAN_CHUNK + t * 4;
    int v[4];
    int s = 0;
    for (int j = 0; j < 4; j++) {
        int idx = base + j;
        v[j] = (idx < Nn) ? deg[idx] + 1 : 0;
        s += v[j];
    }
    sh[t] = s;
    __syncthreads();
    for (int off = 1; off < 256; off <<= 1) {
        int x = (t >= off) ? sh[t - off] : 0;
        __syncthreads();
        sh[t] += x;
        __syncthreads();
    }
    int excl = sh[t] - s;
    if (t == 255) blocksum[b] = sh[255];
    int run = excl;
    for (int j = 0; j < 4; j++) {
        int idx = base + j;
        if (idx < Nn) offs[idx] = run;
        run += v[j];
    }
}

// fused scan2+scan3: per-thread prefix over <=G block sums (L2-hot)
__global__ void scan23(int* __restrict__ offs, const int* __restrict__ bsum,
                       int* __restrict__ cursor, int Nn, int G) {
    int i = blockIdx.x * 256 + threadIdx.x;
    if (i > Nn) return;
    int g = i >> 10;
    int basev = 0;
    for (int k = 0; k < g; k++) basev += bsum[k];
    if (i == Nn) {
        int tot = basev;
        for (int k = g; k < G; k++) tot += bsum[k];
        offs[Nn] = tot;
        return;
    }
    int v = offs[i] + basev;
    offs[i] = v;
    cursor[i] = v;
}

__global__ void fill_csr(const int* __restrict__ ei, int* cursor, int* csr, int E, int Nn) {
    int t = blockIdx.x * 256 + threadIdx.x;
    if (t < E) {
        int s = ei[t];
        int d = ei[E + t];
        int p = atomicAdd(&cursor[d], 1);
        csr[p] = s;
    } else if (t < E + Nn) {
        int nn = t - E;
        int p = atomicAdd(&cursor[nn], 1);
        csr[p] = nn;
    }
}

// ------- prep: all fp32->bf16 conversions + edge degree count (deg pre-zeroed) -------

__global__ __launch_bounds__(256) void prep_all(
    int* __restrict__ deg, const int* __restrict__ ei, int E,
    const float* __restrict__ x, unsigned short* __restrict__ xb, int nx, int nxpad,
    const float* __restrict__ w1, unsigned short* __restrict__ o1, int n1,
    const float* __restrict__ w2, unsigned short* __restrict__ o2, int n2,
    const float* __restrict__ w3, unsigned short* __restrict__ o3, int n3) {
    int id = blockIdx.x * 256 + threadIdx.x;
    int nconv = (nxpad + n1 + n2 + n3) / 8;
    if (id >= nconv) {
        int e = id - nconv;
        if (e < E) atomicAdd(&deg[ei[E + e]], 1);
        return;
    }
    int i = id * 8;
    const float* in;
    unsigned short* out;
    if (i < nxpad) {
        if (i >= nx) {
            *(ushort4*)&xb[i] = make_ushort4(0, 0, 0, 0);
            *(ushort4*)&xb[i + 4] = make_ushort4(0, 0, 0, 0);
            return;
        }
        in = x + i; out = xb + i;
    } else {
        int j = i - nxpad;
        if (j < n1) { in = w1 + j; out = o1 + j; }
        else if (j < n1 + n2) { in = w2 + (j - n1); out = o2 + (j - n1); }
        else { in = w3 + (j - n1 - n2); out = o3 + (j - n1 - n2); }
    }
    float4 a = *(const float4*)in;
    float4 b = *(const float4*)(in + 4);
    *(ushort4*)out = make_ushort4(f2bf(a.x), f2bf(a.y), f2bf(a.z), f2bf(a.w));
    *(ushort4*)(out + 4) = make_ushort4(f2bf(b.x), f2bf(b.y), f2bf(b.z), f2bf(b.w));
}

// BN-apply transform: leaky(sc*y+sh) (+res when RES), pack 2 bf16
template <bool RES>
__device__ __forceinline__ unsigned bnpack2(unsigned short ya, unsigned short yb_,
                                            float sca, float scb, float sha, float shb,
                                            unsigned short ra, unsigned short rb_) {
    float v0 = sca * b2f(ya) + sha; v0 = v0 > 0.f ? v0 : NEG_ACT * v0;
    float v1 = scb * b2f(yb_) + shb; v1 = v1 > 0.f ? v1 : NEG_ACT * v1;
    if (RES) { v0 += b2f(ra); v1 += b2f(rb_); }
    return ((unsigned)f2bf(v1) << 16) | f2bf(v0);
}

// ---------------- MFMA GEMM (TN) + fused attention-logit epilogue ----------------
// HEADS==4: flat grid gm*4, XCD-aware swizzle (4 head-blocks of an m-tile share an XCD).
// FUSE: A = leaky(scale*Yb_in+shift) [+ RWbuf residual when FRES].
// FWOUT: hd==0 blocks also write the transformed A tile to RWbuf (next residual).

template <int K, int CO, int HEADS, bool FUSE, bool FRES, bool FWOUT>
__global__ __launch_bounds__(256) void gemm_mfma(
    const unsigned short* __restrict__ Xb, const unsigned short* __restrict__ Wb,
    unsigned short* __restrict__ Hb, const float* __restrict__ a_s,
    const float* __restrict__ a_d, float* __restrict__ als, float* __restrict__ ald,
    const unsigned short* __restrict__ Yb_in, unsigned short* __restrict__ RWbuf,
    const float* __restrict__ scale, const float* __restrict__ shift, int Nn) {
    constexpr int BM = 128, BK = 64, LD = 72, SLD = 68;
    __shared__ __align__(16) char smem[4 * 32 * SLD * 4];
    unsigned short* As = (unsigned short*)smem;
    unsigned short* Bs = As + BM * LD;
    int tid = threadIdx.x;
    int wave = tid >> 6, lane = tid & 63;
    int quad = lane >> 4, l16 = lane & 15;
    int mt, hd;
    if (HEADS == 4) {
        int gm = gridDim.x >> 2;
        int gm8 = gm & ~7;
        int nfull = gm8 * 4;
        int id = blockIdx.x;
        if (id < nfull) {
            int r = id & 31;
            mt = (id >> 5) * 8 + (r & 7);
            hd = r >> 3;
        } else {
            int t2 = id - nfull;
            mt = gm8 + (t2 >> 2);
            hd = t2 & 3;
        }
    } else {
        mt = blockIdx.x;
        hd = 0;
    }
    int m0 = mt * BM, n0 = hd * 64;
    int arow = tid >> 3;
    int achk = (tid & 7) * 8;
    f32x4 acc[2][4] = {};
    for (int k0 = 0; k0 < K; k0 += BK) {
        __syncthreads();
        if (FUSE) {
            int cb = k0 + achk;
            float4 sc0 = *(const float4*)&scale[cb];
            float4 sc1 = *(const float4*)&scale[cb + 4];
            float4 sh0 = *(const float4*)&shift[cb];
            float4 sh1 = *(const float4*)&shift[cb + 4];
#pragma unroll
            for (int p = 0; p < 4; p++) {
                int r = arow + p * 32;
                int m = m0 + r;
                uint4 o = make_uint4(0, 0, 0, 0);
                if (m < Nn) {
                    ushort4 ua = *(const ushort4*)&Yb_in[(size_t)m * 256 + cb];
                    ushort4 ub = *(const ushort4*)&Yb_in[(size_t)m * 256 + cb + 4];
                    ushort4 ra = make_ushort4(0, 0, 0, 0), rb = ra;
                    if (FRES) {
                        ra = *(const ushort4*)&RWbuf[(size_t)m * 256 + cb];
                        rb = *(const ushort4*)&RWbuf[(size_t)m * 256 + cb + 4];
                    }
                    o.x = bnpack2<FRES>(ua.x, ua.y, sc0.x, sc0.y, sh0.x, sh0.y, ra.x, ra.y);
                    o.y = bnpack2<FRES>(ua.z, ua.w, sc0.z, sc0.w, sh0.z, sh0.w, ra.z, ra.w);
                    o.z = bnpack2<FRES>(ub.x, ub.y, sc1.x, sc1.y, sh1.x, sh1.y, rb.x, rb.y);
                    o.w = bnpack2<FRES>(ub.z, ub.w, sc1.z, sc1.w, sh1.z, sh1.w, rb.z, rb.w);
                    if (FWOUT && hd == 0)
                        *(uint4*)&RWbuf[(size_t)m * 256 + cb] = o;
                }
                *(uint4*)&As[r * LD + achk] = o;
            }
        } else {
#pragma unroll
            for (int p = 0; p < 4; p++) {
                int r = arow + p * 32;
                *(int4*)&As[r * LD + achk] = *(const int4*)&Xb[(size_t)(m0 + r) * K + k0 + achk];
            }
        }
#pragma unroll
        for (int p = 0; p < 2; p++) {
            int r = arow + p * 32;
            *(int4*)&Bs[r * LD + achk] = *(const int4*)&Wb[(size_t)(n0 + r) * K + k0 + achk];
        }
        __syncthreads();
#pragma unroll
        for (int ks = 0; ks < 2; ks++) {
            short8 af[2], bfr[4];
#pragma unroll
            for (int i = 0; i < 2; i++)
                af[i] = *(const short8*)&As[(wave * 32 + i * 16 + l16) * LD + ks * 32 + quad * 8];
#pragma unroll
            for (int j = 0; j < 4; j++)
                bfr[j] = *(const short8*)&Bs[(j * 16 + l16) * LD + ks * 32 + quad * 8];
#pragma unroll
            for (int i = 0; i < 2; i++)
#pragma unroll
                for (int j = 0; j < 4; j++)
                    acc[i][j] = __builtin_amdgcn_mfma_f32_16x16x32_bf16(af[i], bfr[j], acc[i][j], 0, 0, 0);
        }
    }
    __syncthreads();

    float asv[4], adv[4];
#pragma unroll
    for (int j = 0; j < 4; j++) {
        asv[j] = a_s[hd * 64 + j * 16 + l16];
        adv[j] = a_d[hd * 64 + j * 16 + l16];
    }
#pragma unroll
    for (int i = 0; i < 2; i++)
#pragma unroll
        for (int r = 0; r < 4; r++) {
            float ps = acc[i][0][r] * asv[0] + acc[i][1][r] * asv[1] +
                       acc[i][2][r] * asv[2] + acc[i][3][r] * asv[3];
            float pd = acc[i][0][r] * adv[0] + acc[i][1][r] * adv[1] +
                       acc[i][2][r] * adv[2] + acc[i][3][r] * adv[3];
#pragma unroll
            for (int mm = 1; mm < 16; mm <<= 1) {
                ps += __shfl_xor(ps, mm);
                pd += __shfl_xor(pd, mm);
            }
            if (l16 == 0) {
                int m = m0 + wave * 32 + i * 16 + quad * 4 + r;
                als[m * HEADS + hd] = ps;
                ald[m * HEADS + hd] = pd;
            }
        }

    float* stg = (float*)smem + wave * 32 * SLD;
#pragma unroll
    for (int i = 0; i < 2; i++)
#pragma unroll
        for (int j = 0; j < 4; j++)
#pragma unroll
            for (int r = 0; r < 4; r++)
                stg[(i * 16 + quad * 4 + r) * SLD + j * 16 + l16] = acc[i][j][r];
    int g = lane >> 3, c8 = (lane & 7) * 8;
#pragma unroll
    for (int p = 0; p < 4; p++) {
        int row = p * 8 + g;
        float4 v0 = *(const float4*)&stg[row * SLD + c8];
        float4 v1 = *(const float4*)&stg[row * SLD + c8 + 4];
        uint4 o;
        o.x = ((unsigned)f2bf(v0.y) << 16) | f2bf(v0.x);
        o.y = ((unsigned)f2bf(v0.w) << 16) | f2bf(v0.z);
        o.z = ((unsigned)f2bf(v1.y) << 16) | f2bf(v1.x);
        o.w = ((unsigned)f2bf(v1.w) << 16) | f2bf(v1.z);
        *(uint4*)&Hb[(size_t)(m0 + wave * 32 + row) * CO + n0 + c8] = o;
    }
}

// ---------------- edge-softmax aggregation (inline w, unroll-8, bf16 out) --------

#define EDGE4(sA, sB, sC, sD)                                                        \
    {                                                                                \
        float a0 = als[(sA)*4 + hd], a1 = als[(sB)*4 + hd];                          \
        float a2 = als[(sC)*4 + hd], a3 = als[(sD)*4 + hd];                          \
        ushort4 h0 = *(const ushort4*)&Hb[(size_t)(sA)*256 + c4];                    \
        ushort4 h1 = *(const ushort4*)&Hb[(size_t)(sB)*256 + c4];                    \
        ushort4 h2 = *(const ushort4*)&Hb[(size_t)(sC)*256 + c4];                    \
        ushort4 h3 = *(const ushort4*)&Hb[(size_t)(sD)*256 + c4];                    \
        float e0 = a0 + aldn; e0 = e0 > 0.f ? e0 : NEG_ATT * e0;                     \
        float e1 = a1 + aldn; e1 = e1 > 0.f ? e1 : NEG_ATT * e1;                     \
        float e2 = a2 + aldn; e2 = e2 > 0.f ? e2 : NEG_ATT * e2;                     \
        float e3 = a3 + aldn; e3 = e3 > 0.f ? e3 : NEG_ATT * e3;                     \
        float w0 = __expf(e0), w1 = __expf(e1), w2 = __expf(e2), w3 = __expf(e3);    \
        den += (w0 + w1) + (w2 + w3);                                                \
        acc.x += w0 * b2f(h0.x) + w1 * b2f(h1.x) + w2 * b2f(h2.x) + w3 * b2f(h3.x);  \
        acc.y += w0 * b2f(h0.y) + w1 * b2f(h1.y) + w2 * b2f(h2.y) + w3 * b2f(h3.y);  \
        acc.z += w0 * b2f(h0.z) + w1 * b2f(h1.z) + w2 * b2f(h2.z) + w3 * b2f(h3.z);  \
        acc.w += w0 * b2f(h0.w) + w1 * b2f(h1.w) + w2 * b2f(h2.w) + w3 * b2f(h3.w);  \
    }

__global__ __launch_bounds__(256) void aggregate_h4(
    const unsigned short* __restrict__ Hb, const float* __restrict__ als,
    const float* __restrict__ ald, const int* __restrict__ offs,
    const int* __restrict__ csr, unsigned short* __restrict__ Yb, int Nn) {
    int wave = threadIdx.x >> 6;
    int lane = threadIdx.x & 63;
    int n = blockIdx.x * 4 + wave;
    if (n >= Nn) return;
    int hd = lane >> 4;
    int c4 = lane * 4;
    float aldn = ald[n * 4 + hd];
    int beg = offs[n], end = offs[n + 1];
    float4 acc = make_float4(0.f, 0.f, 0.f, 0.f);
    float den = 0.f;
    for (int b = beg; b < end; b += 64) {
        int cnt = min(64, end - b);
        int idx = 0;
        if (lane < cnt) idx = csr[b + lane];
        int j = 0;
        for (; j + 8 <= cnt; j += 8) {
            int s0 = __shfl(idx, j), s1 = __shfl(idx, j + 1);
            int s2 = __shfl(idx, j + 2), s3 = __shfl(idx, j + 3);
            int s4 = __shfl(idx, j + 4), s5 = __shfl(idx, j + 5);
            int s6 = __shfl(idx, j + 6), s7 = __shfl(idx, j + 7);
            EDGE4(s0, s1, s2, s3);
            EDGE4(s4, s5, s6, s7);
        }
        for (; j + 4 <= cnt; j += 4) {
            int s0 = __shfl(idx, j), s1 = __shfl(idx, j + 1);
            int s2 = __shfl(idx, j + 2), s3 = __shfl(idx, j + 3);
            EDGE4(s0, s1, s2, s3);
        }
        for (; j < cnt; j++) {
            int s = __shfl(idx, j);
            float e = als[s * 4 + hd] + aldn;
            e = e > 0.f ? e : NEG_ATT * e;
            float w = __expf(e);
            den += w;
            ushort4 hv = *(const ushort4*)&Hb[(size_t)s * 256 + c4];
            acc.x += w * b2f(hv.x); acc.y += w * b2f(hv.y);
            acc.z += w * b2f(hv.z); acc.w += w * b2f(hv.w);
        }
    }
    float inv = 1.f / den;
    *(ushort4*)&Yb[(size_t)n * 256 + c4] = make_ushort4(
        f2bf(acc.x * inv), f2bf(acc.y * inv), f2bf(acc.z * inv), f2bf(acc.w * inv));
}

// heads=1: final layer, writes fp32 out (keeps bias).
__global__ __launch_bounds__(256) void aggregate_h1(
    const unsigned short* __restrict__ Hb, const float* __restrict__ als,
    const float* __restrict__ ald, const int* __restrict__ offs,
    const int* __restrict__ csr, const float* __restrict__ bias,
    float* __restrict__ Yout, int Nn) {
    int wave = threadIdx.x >> 6;
    int lane = threadIdx.x & 63;
    int sub = lane >> 4, lane16 = lane & 15;
    int n = blockIdx.x * 16 + wave * 4 + sub;
    if (n >= Nn) return;
    int c4 = lane16 * 4;
    float aldn = ald[n];
    int beg = offs[n], end = offs[n + 1];
    float4 acc = make_float4(0.f, 0.f, 0.f, 0.f);
    float den = 0.f;
    for (int b = beg; b < end; b += 16) {
        int cnt = min(16, end - b);
        int idx = 0;
        if (lane16 < cnt) idx = csr[b + lane16];
        int j = 0;
        for (; j + 4 <= cnt; j += 4) {
            int s0 = __shfl(idx, (sub << 4) + j);
            int s1 = __shfl(idx, (sub << 4) + j + 1);
            int s2 = __shfl(idx, (sub << 4) + j + 2);
            int s3 = __shfl(idx, (sub << 4) + j + 3);
            float a0 = als[s0], a1 = als[s1], a2 = als[s2], a3 = als[s3];
            ushort4 h0 = *(const ushort4*)&Hb[(size_t)s0 * 64 + c4];
            ushort4 h1 = *(const ushort4*)&Hb[(size_t)s1 * 64 + c4];
            ushort4 h2 = *(const ushort4*)&Hb[(size_t)s2 * 64 + c4];
            ushort4 h3 = *(const ushort4*)&Hb[(size_t)s3 * 64 + c4];
            float e0 = a0 + aldn; e0 = e0 > 0.f ? e0 : NEG_ATT * e0;
            float e1 = a1 + aldn; e1 = e1 > 0.f ? e1 : NEG_ATT * e1;
            float e2 = a2 + aldn; e2 = e2 > 0.f ? e2 : NEG_ATT * e2;
            float e3 = a3 + aldn; e3 = e3 > 0.f ? e3 : NEG_ATT * e3;
            float w0 = __expf(e0), w1 = __expf(e1), w2 = __expf(e2), w3 = __expf(e3);
            den += (w0 + w1) + (w2 + w3);
            acc.x += w0 * b2f(h0.x) + w1 * b2f(h1.x) + w2 * b2f(h2.x) + w3 * b2f(h3.x);
            acc.y += w0 * b2f(h0.y) + w1 * b2f(h1.y) + w2 * b2f(h2.y) + w3 * b2f(h3.y);
            acc.z += w0 * b2f(h0.z) + w1 * b2f(h1.z) + w2 * b2f(h2.z) + w3 * b2f(h3.z);
            acc.w += w0 * b2f(h0.w) + w1 * b2f(h1.w) + w2 * b2f(h2.w) + w3 * b2f(h3.w);
        }
        for (; j < cnt; j++) {
            int s = __shfl(idx, (sub << 4) + j);
            float e = als[s] + aldn;
            e = e > 0.f ? e : NEG_ATT * e;
            float w = __expf(e);
            den += w;
            ushort4 hv = *(const ushort4*)&Hb[(size_t)s * 64 + c4];
            acc.x += w * b2f(hv.x); acc.y += w * b2f(hv.y);
            acc.z += w * b2f(hv.z); acc.w += w * b2f(hv.w);
        }
    }
    float inv = 1.f / den;
    float4 bv = *(const float4*)&bias[c4];
    float4 o = make_float4(acc.x * inv + bv.x, acc.y * inv + bv.y,
                           acc.z * inv + bv.z, acc.w * inv + bv.w);
    *(float4*)&Yout[(size_t)n * 64 + c4] = o;
}

// ---------------- BatchNorm stats over bf16 y (coalesced, 1024 blocks) ----------------

__global__ __launch_bounds__(256) void bn_stats(const unsigned short* __restrict__ Yb,
                                                float* __restrict__ partial, int Nn) {
    __shared__ float red[4 * 512];
    int t = threadIdx.x;
    int g = blockIdx.x;
    int rows_per = (Nn + gridDim.x - 1) / gridDim.x;
    int r0 = g * rows_per;
    int r1 = min(r0 + rows_per, Nn);
    int sub = t >> 6;
    int c4 = (t & 63) * 4;
    float4 s = make_float4(0.f, 0.f, 0.f, 0.f);
    float4 q = make_float4(0.f, 0.f, 0.f, 0.f);
    for (int r = r0 + sub; r < r1; r += 4) {
        ushort4 u = *(const ushort4*)&Yb[(size_t)r * 256 + c4];
        float vx = b2f(u.x), vy = b2f(u.y), vz = b2f(u.z), vw = b2f(u.w);
        s.x += vx; s.y += vy; s.z += vz; s.w += vw;
        q.x += vx * vx; q.y += vy * vy; q.z += vz * vz; q.w += vw * vw;
    }
    float* rs = &red[sub * 512];
    rs[c4 + 0] = s.x; rs[c4 + 1] = s.y; rs[c4 + 2] = s.z; rs[c4 + 3] = s.w;
    rs[256 + c4 + 0] = q.x; rs[256 + c4 + 1] = q.y;
    rs[256 + c4 + 2] = q.z; rs[256 + c4 + 3] = q.w;
    __syncthreads();
    float v0 = red[t] + red[512 + t] + red[1024 + t] + red[1536 + t];
    float v1 = red[256 + t] + red[768 + t] + red[1280 + t] + red[1792 + t];
    partial[(size_t)g * 512 + t] = v0;
    partial[(size_t)g * 512 + 256 + t] = v1;
}

__global__ __launch_bounds__(256) void bn_reduce_final(
    const float* __restrict__ partial, int NP, const float* __restrict__ gamma,
    const float* __restrict__ beta, float* scale, float* shift, int Nn) {
    __shared__ float sh[8];
    int ch = blockIdx.x;
    int t = threadIdx.x;
    int wave = t >> 6, lane = t & 63;
    float s = 0.f, q = 0.f;
    for (int i = t; i < NP; i += 256) {
        s += partial[(size_t)i * 512 + ch];
        q += partial[(size_t)i * 512 + 256 + ch];
    }
    for (int off = 32; off; off >>= 1) {
        s += __shfl_down(s, off);
        q += __shfl_down(q, off);
    }
    if (lane == 0) { sh[wave] = s; sh[4 + wave] = q; }
    __syncthreads();
    if (t == 0) {
        s = sh[0] + sh[1] + sh[2] + sh[3];
        q = sh[4] + sh[5] + sh[6] + sh[7];
        float inv_n = 1.f / (float)Nn;
        float mu = s * inv_n;
        float var = q * inv_n - mu * mu;
        float sc = gamma[ch] * rsqrtf(var + 1e-5f);
        scale[ch] = sc;
        shift[ch] = beta[ch] - mu * sc;
    }
}

// ---------------- launch ----------------

extern "C" void kernel_launch(void* const* d_in, const int* in_sizes, int n_in,
                              void* d_out, int out_size, void* d_ws, size_t ws_size,
                              hipStream_t stream) {
    const float* x    = (const float*)d_in[0];
    const int*   ei   = (const int*)d_in[1];
    const float* W1   = (const float*)d_in[2];
    const float* a1s  = (const float*)d_in[3];
    const float* a1d  = (const float*)d_in[4];
    const float* W2   = (const float*)d_in[6];
    const float* a2s  = (const float*)d_in[7];
    const float* a2d  = (const float*)d_in[8];
    const float* W3   = (const float*)d_in[10];
    const float* a3s  = (const float*)d_in[11];
    const float* a3d  = (const float*)d_in[12];
    const float* b3   = (const float*)d_in[13];
    const float* gamma = (const float*)d_in[14];
    const float* beta  = (const float*)d_in[15];
    float* out = (float*)d_out;

    const int Nn = in_sizes[0] / 128;
    const int E  = in_sizes[1] / 2;
    const int Ep = E + Nn;
    const int Mpad = (Nn + 127) & ~127;

    size_t off = 0;
    char* base = (char*)d_ws;
    auto alloc = [&](size_t bytes) -> void* {
        void* p = base + off;
        off = (off + bytes + 255) & ~(size_t)255;
        return p;
    };
    unsigned short* Hb   = (unsigned short*)alloc((size_t)Mpad * 256 * 2);
    unsigned short* Yb   = (unsigned short*)alloc((size_t)Nn * 256 * 2);
    unsigned short* xb1  = (unsigned short*)alloc((size_t)Mpad * 128 * 2);
    unsigned short* xbig = (unsigned short*)alloc((size_t)Mpad * 256 * 2);
    unsigned short* wb1  = (unsigned short*)alloc((size_t)256 * 128 * 2);
    unsigned short* wb2  = (unsigned short*)alloc((size_t)256 * 256 * 2);
    unsigned short* wb3  = (unsigned short*)alloc((size_t)64 * 256 * 2);
    float* als    = (float*)alloc((size_t)Mpad * 4 * 4);
    float* ald    = (float*)alloc((size_t)Mpad * 4 * 4);
    int*   deg    = (int*)alloc((size_t)Nn * 4);
    int*   offs   = (int*)alloc((size_t)(Nn + 1) * 4);
    int*   cursor = (int*)alloc((size_t)Nn * 4);
    int*   bsum   = (int*)alloc(64 * 4);
    int*   csr    = (int*)alloc((size_t)Ep * 4);
    const int NP = 1024;
    float* partial = (float*)alloc((size_t)NP * 512 * 4);
    float* scale  = (float*)alloc(256 * 4);
    float* shift  = (float*)alloc(256 * 4);
    (void)ws_size;

    const int G = (Nn + SCAN_CHUNK - 1) / SCAN_CHUNK;

    // ---- deg zero + prep (conversions + edge counting) ----
    hipMemsetAsync(deg, 0, (size_t)Nn * 4, stream);
    {
        int nxpad = Mpad * 128;
        int wtot = 256 * 128 + 256 * 256 + 64 * 256;
        int nconv = (nxpad + wtot) / 8;
        prep_all<<<(nconv + E + 255) / 256, 256, 0, stream>>>(
            deg, ei, E, x, xb1, Nn * 128, nxpad,
            W1, wb1, 256 * 128, W2, wb2, 256 * 256, W3, wb3, 64 * 256);
    }

    // ---- CSR build ----
    scan1<<<G, 256, 0, stream>>>(deg, offs, bsum, Nn);
    scan23<<<(Nn + 1 + 255) / 256, 256, 0, stream>>>(offs, bsum, cursor, Nn, G);
    fill_csr<<<(Ep + 255) / 256, 256, 0, stream>>>(ei, cursor, csr, E, Nn);

    const int gm = Mpad / 128;
    const int nagg4 = (Nn + 3) / 4;
    const int nagg1 = (Nn + 15) / 16;

    // ---- Layer 1 ----
    gemm_mfma<128, 256, 4, false, false, false><<<gm * 4, 256, 0, stream>>>(
        xb1, wb1, Hb, a1s, a1d, als, ald, nullptr, nullptr, nullptr, nullptr, 0);
    aggregate_h4<<<nagg4, 256, 0, stream>>>(Hb, als, ald, offs, csr, Yb, Nn);
    bn_stats<<<NP, 256, 0, stream>>>(Yb, partial, Nn);
    bn_reduce_final<<<256, 256, 0, stream>>>(partial, NP, gamma, beta, scale, shift, Nn);

    // ---- Layer 2 (layer-1 BN-apply fused into A-staging; hd==0 writes xbig) ----
    gemm_mfma<256, 256, 4, true, false, true><<<gm * 4, 256, 0, stream>>>(
        nullptr, wb2, Hb, a2s, a2d, als, ald, Yb, xbig, scale, shift, Nn);
    aggregate_h4<<<nagg4, 256, 0, stream>>>(Hb, als, ald, offs, csr, Yb, Nn);
    bn_stats<<<NP, 256, 0, stream>>>(Yb, partial, Nn);
    bn_reduce_final<<<256, 256, 0, stream>>>(partial, NP, gamma, beta, scale, shift, Nn);

    // ---- Layer 3 (layer-2 BN-apply + residual fused into A-staging) ----
    gemm_mfma<256, 64, 1, true, true, false><<<gm, 256, 0, stream>>>(
        nullptr, wb3, Hb, a3s, a3d, als, ald, Yb, xbig, scale, shift, Nn);
    aggregate_h1<<<nagg1, 256, 0, stream>>>(Hb, als, ald, offs, csr, b3, out, Nn);
}